// Round 4
// baseline (786.566 us; speedup 1.0000x reference)
//
#include <hip/hip_runtime.h>
#include <math.h>

// GCN 2-layer: N=100000 nodes, E=3200000 edges, 128 -> 16 -> 7
// R4: bucketed LDS aggregation + 1024-thr blocks, 4-way gather batching,
//     non-temporal streams for ebuf.
constexpr int NN = 100000;
constexpr int NE = 3200000;
constexpr int DF = 128;
constexpr int NH = 16;
constexpr int NC = 7;

constexpr int BN    = 128;                      // nodes per bucket (pow2)
constexpr int NB    = (NN + BN - 1) / BN;       // 782 buckets
constexpr int CAP   = 4608;                     // slots per bucket
constexpr int CHUNK = 16384;                    // edges per append block
constexpr int AB    = (NE + CHUNK - 1) / CHUNK; // 196

__device__ inline uint2 nt_load_u2(const uint2* p) {
    unsigned long long v = __builtin_nontemporal_load((const unsigned long long*)p);
    uint2 r; r.x = (unsigned)v; r.y = (unsigned)(v >> 32);
    return r;
}

// ---------------- zero bucket cursors ----------------
__global__ void k_zero(int* __restrict__ gcur) {
    int t = blockIdx.x * blockDim.x + threadIdx.x;
    if (t < NB) gcur[t] = 0;
}

// ---------------- bucket append ----------------
__global__ void __launch_bounds__(1024)
k_append(const int* __restrict__ src,
         const int* __restrict__ dst,
         const float* __restrict__ w,
         int* __restrict__ gcur,
         uint2* __restrict__ ebuf) {
    __shared__ int hist[NB];
    __shared__ int basev[NB];
    for (int i = threadIdx.x; i < NB; i += 1024) hist[i] = 0;
    __syncthreads();
    int e0 = blockIdx.x * CHUNK;
    int e1 = min(e0 + CHUNK, NE);
    for (int e = e0 + (int)threadIdx.x; e < e1; e += 1024)
        atomicAdd(&hist[__builtin_nontemporal_load(dst + e) >> 7], 1);
    __syncthreads();
    for (int b = threadIdx.x; b < NB; b += 1024) {
        int c = hist[b];
        basev[b] = (c > 0) ? atomicAdd(&gcur[b], c) : 0;
        hist[b] = 0;
    }
    __syncthreads();
    for (int e = e0 + (int)threadIdx.x; e < e1; e += 1024) {
        int d = __builtin_nontemporal_load(dst + e);
        int b = d >> 7;
        int r = atomicAdd(&hist[b], 1);
        int pos = basev[b] + r;
        if (pos < CAP) {
            unsigned lo = ((unsigned)(d & (BN - 1)) << 17) |
                          (unsigned)__builtin_nontemporal_load(src + e);
            unsigned hi = __float_as_uint(__builtin_nontemporal_load(w + e));
            unsigned long long v = (unsigned long long)lo | ((unsigned long long)hi << 32);
            __builtin_nontemporal_store(v, (unsigned long long*)&ebuf[(size_t)b * CAP + pos]);
        }
    }
}

// ---------------- per-bucket degree -> dinv ----------------
__global__ void __launch_bounds__(1024)
k_deg(const int* __restrict__ gcur,
      const uint2* __restrict__ ebuf,
      float* __restrict__ dinv) {
    __shared__ float degs[BN];
    int b = blockIdx.x;
    if (threadIdx.x < BN) degs[threadIdx.x] = 1.0f;  // self-loop
    __syncthreads();
    int cnt = min(gcur[b], CAP);
    const uint2* eb = ebuf + (size_t)b * CAP;
    for (int i = threadIdx.x; i < cnt; i += 1024) {
        uint2 v = nt_load_u2(eb + i);
        atomicAdd(&degs[(v.x >> 17) & (BN - 1)], __uint_as_float(v.y));
    }
    __syncthreads();
    if (threadIdx.x < BN) {
        int n = b * BN + threadIdx.x;
        if (n < NN) dinv[n] = rsqrtf(degs[threadIdx.x]);
    }
}

// ---------------- h1' = dinv * (x @ W1) ----------------
__global__ void k_proj1(const float* __restrict__ x,
                        const float* __restrict__ W1,
                        const float* __restrict__ dinv,
                        float* __restrict__ h1p) {
    __shared__ float Ws[DF * NH];
    for (int i = threadIdx.x; i < DF * NH; i += blockDim.x) Ws[i] = W1[i];
    __syncthreads();
    int t = blockIdx.x * blockDim.x + threadIdx.x;
    if (t >= NN * NH) return;
    int n = t >> 4;
    int f = t & 15;
    const float4* xr = (const float4*)(x + (size_t)n * DF);
    float acc = 0.0f;
#pragma unroll
    for (int k4 = 0; k4 < DF / 4; ++k4) {
        float4 xv = xr[k4];
        acc += xv.x * Ws[(k4 * 4 + 0) * NH + f];
        acc += xv.y * Ws[(k4 * 4 + 1) * NH + f];
        acc += xv.z * Ws[(k4 * 4 + 2) * NH + f];
        acc += xv.w * Ws[(k4 * 4 + 3) * NH + f];
    }
    h1p[t] = acc * dinv[n];
}

// ---------------- layer-1 aggregate in LDS, 16 lanes/edge, 4-way batch ----------------
__global__ void __launch_bounds__(1024)
k_agg1(const int* __restrict__ gcur,
       const uint2* __restrict__ ebuf,
       const float* __restrict__ h1p,
       float* __restrict__ acc1) {
    __shared__ float acc[BN * NH];  // 8 KB
    int b = blockIdx.x;
    int gbase = b * BN * NH;
#pragma unroll
    for (int r = 0; r < 2; ++r) {
        int i = r * 1024 + threadIdx.x;
        int gi = gbase + i;
        acc[i] = (gi < NN * NH) ? h1p[gi] : 0.0f;  // self term
    }
    __syncthreads();
    int cnt = min(gcur[b], CAP);
    const uint2* eb = ebuf + (size_t)b * CAP;
    int f = threadIdx.x & 15;
    int g = threadIdx.x >> 4;  // 0..63
    int i = g;
    for (; i + 192 < cnt; i += 256) {
        uint2 v0 = nt_load_u2(eb + i);
        uint2 v1 = nt_load_u2(eb + i + 64);
        uint2 v2 = nt_load_u2(eb + i + 128);
        uint2 v3 = nt_load_u2(eb + i + 192);
        float g0 = h1p[(v0.x & 0x1FFFF) * NH + f];
        float g1 = h1p[(v1.x & 0x1FFFF) * NH + f];
        float g2 = h1p[(v2.x & 0x1FFFF) * NH + f];
        float g3 = h1p[(v3.x & 0x1FFFF) * NH + f];
        atomicAdd(&acc[((v0.x >> 17) & (BN - 1)) * NH + f], __uint_as_float(v0.y) * g0);
        atomicAdd(&acc[((v1.x >> 17) & (BN - 1)) * NH + f], __uint_as_float(v1.y) * g1);
        atomicAdd(&acc[((v2.x >> 17) & (BN - 1)) * NH + f], __uint_as_float(v2.y) * g2);
        atomicAdd(&acc[((v3.x >> 17) & (BN - 1)) * NH + f], __uint_as_float(v3.y) * g3);
    }
    for (; i < cnt; i += 64) {
        uint2 v = nt_load_u2(eb + i);
        float gg = h1p[(v.x & 0x1FFFF) * NH + f];
        atomicAdd(&acc[((v.x >> 17) & (BN - 1)) * NH + f], __uint_as_float(v.y) * gg);
    }
    __syncthreads();
#pragma unroll
    for (int r = 0; r < 2; ++r) {
        int i2 = r * 1024 + threadIdx.x;
        int gi = gbase + i2;
        if (gi < NN * NH) __builtin_nontemporal_store(acc[i2], acc1 + gi);
    }
}

// ---------------- h2' = dinv * (relu(dinv*acc1 + b1) @ W2), padded to 8 ----------------
__global__ void k_relu_proj2(const float* __restrict__ acc1,
                             const float* __restrict__ dinv,
                             const float* __restrict__ b1,
                             const float* __restrict__ W2,
                             float* __restrict__ h2p) {
    int n = blockIdx.x * blockDim.x + threadIdx.x;
    if (n >= NN) return;
    float di = dinv[n];
    float hr[NH];
#pragma unroll
    for (int k = 0; k < NH; ++k)
        hr[k] = fmaxf(di * acc1[n * NH + k] + b1[k], 0.0f);
#pragma unroll
    for (int c = 0; c < NC; ++c) {
        float a = 0.0f;
#pragma unroll
        for (int k = 0; k < NH; ++k) a += hr[k] * W2[k * NC + c];
        h2p[n * 8 + c] = di * a;
    }
    h2p[n * 8 + 7] = 0.0f;
}

// ---------------- layer-2 aggregate in LDS + bias + log_softmax, 8 lanes/edge ----------------
__global__ void __launch_bounds__(1024)
k_agg2_lsm(const int* __restrict__ gcur,
           const uint2* __restrict__ ebuf,
           const float* __restrict__ h2p,
           const float* __restrict__ dinv,
           const float* __restrict__ b2,
           float* __restrict__ out) {
    __shared__ float acc[BN * 8];  // 4 KB
    int b = blockIdx.x;
    int gbase = b * BN * 8;
    {
        int i = threadIdx.x;  // 1024 == BN*8
        int gi = gbase + i;
        acc[i] = (gi < NN * 8) ? h2p[gi] : 0.0f;  // self term (pad lane = 0)
    }
    __syncthreads();
    int cnt = min(gcur[b], CAP);
    const uint2* eb = ebuf + (size_t)b * CAP;
    int c = threadIdx.x & 7;
    int g = threadIdx.x >> 3;  // 0..127
    int i = g;
    for (; i + 384 < cnt; i += 512) {
        uint2 v0 = nt_load_u2(eb + i);
        uint2 v1 = nt_load_u2(eb + i + 128);
        uint2 v2 = nt_load_u2(eb + i + 256);
        uint2 v3 = nt_load_u2(eb + i + 384);
        float g0 = h2p[(v0.x & 0x1FFFF) * 8 + c];
        float g1 = h2p[(v1.x & 0x1FFFF) * 8 + c];
        float g2 = h2p[(v2.x & 0x1FFFF) * 8 + c];
        float g3 = h2p[(v3.x & 0x1FFFF) * 8 + c];
        atomicAdd(&acc[((v0.x >> 17) & (BN - 1)) * 8 + c], __uint_as_float(v0.y) * g0);
        atomicAdd(&acc[((v1.x >> 17) & (BN - 1)) * 8 + c], __uint_as_float(v1.y) * g1);
        atomicAdd(&acc[((v2.x >> 17) & (BN - 1)) * 8 + c], __uint_as_float(v2.y) * g2);
        atomicAdd(&acc[((v3.x >> 17) & (BN - 1)) * 8 + c], __uint_as_float(v3.y) * g3);
    }
    for (; i < cnt; i += 128) {
        uint2 v = nt_load_u2(eb + i);
        float gg = h2p[(v.x & 0x1FFFF) * 8 + c];
        atomicAdd(&acc[((v.x >> 17) & (BN - 1)) * 8 + c], __uint_as_float(v.y) * gg);
    }
    __syncthreads();
    int dl = threadIdx.x;
    if (dl < BN) {
        int n = b * BN + dl;
        if (n < NN) {
            float di = dinv[n];
            float v[NC];
            float m = -1e30f;
#pragma unroll
            for (int cc = 0; cc < NC; ++cc) {
                v[cc] = di * acc[dl * 8 + cc] + b2[cc];
                m = fmaxf(m, v[cc]);
            }
            float s_ = 0.0f;
#pragma unroll
            for (int cc = 0; cc < NC; ++cc) s_ += __expf(v[cc] - m);
            float lse = m + __logf(s_);
#pragma unroll
            for (int cc = 0; cc < NC; ++cc) out[n * NC + cc] = v[cc] - lse;
        }
    }
}

extern "C" void kernel_launch(void* const* d_in, const int* in_sizes, int n_in,
                              void* d_out, int out_size, void* d_ws, size_t ws_size,
                              hipStream_t stream) {
    const float* x  = (const float*)d_in[0];
    const int*   ei = (const int*)d_in[1];
    const float* ew = (const float*)d_in[2];
    const float* W1 = (const float*)d_in[3];
    const float* b1 = (const float*)d_in[4];
    const float* W2 = (const float*)d_in[5];
    const float* b2 = (const float*)d_in[6];
    float* out = (float*)d_out;

    const int* srcp = ei;
    const int* dstp = ei + NE;

    // ws layout (4B units), total 10,508,288 fl = 42.0 MB
    float* ws   = (float*)d_ws;
    float* dinv = ws;                          // 100352
    float* h1p  = ws + 100352;                 // 1600000
    float* acc1 = ws + 1700352;                // 1600000
    int*   gcur = (int*)(ws + 3300352);        // 1024
    uint2* ebuf = (uint2*)(ws + 3301376);      // NB*CAP uint2
    float* h2p  = h1p;                         // overlay: h1p dead after k_agg1

    const int B = 256;
    auto cdiv = [](long long a, long long b) { return (int)((a + b - 1) / b); };

    k_zero<<<1, 1024, 0, stream>>>(gcur);
    k_append<<<AB, 1024, 0, stream>>>(srcp, dstp, ew, gcur, ebuf);
    k_deg<<<NB, 1024, 0, stream>>>(gcur, ebuf, dinv);
    k_proj1<<<cdiv((long long)NN * NH, B), B, 0, stream>>>(x, W1, dinv, h1p);
    k_agg1<<<NB, 1024, 0, stream>>>(gcur, ebuf, h1p, acc1);
    k_relu_proj2<<<cdiv(NN, B), B, 0, stream>>>(acc1, dinv, b1, W2, h2p);
    k_agg2_lsm<<<NB, 1024, 0, stream>>>(gcur, ebuf, h2p, dinv, b2, out);
}